// Round 15
// baseline (300.785 us; speedup 1.0000x reference)
//
#include <hip/hip_runtime.h>
#include <hip/hip_bf16.h>

#define NPTS 8192
#define DIM  512
#define NHEAD 8
#define HDIM 64
#define NSPLIT 4

typedef short bf16x8 __attribute__((ext_vector_type(8)));   // 8 bf16 = 4 VGPRs
typedef float f32x4  __attribute__((ext_vector_type(4)));   // MFMA C/D

#define GLOBAL_AS __attribute__((address_space(1)))
#define LDS_AS    __attribute__((address_space(3)))

#if __has_builtin(__builtin_amdgcn_exp2f)
#define EXP2F(x) __builtin_amdgcn_exp2f(x)
#else
#define EXP2F(x) __expf((x) * 0.6931471805599453f)
#endif

// fp32 -> bf16 round-nearest-even (scalar)
__device__ __forceinline__ unsigned short f2bf(float f) {
    union { float f; unsigned int u; } v; v.f = f;
    unsigned int r = v.u + 0x7FFFu + ((v.u >> 16) & 1u);
    return (unsigned short)(r >> 16);
}
__device__ __forceinline__ float bf2f(unsigned short u) {
    union { unsigned int i; float f; } v; v.i = ((unsigned int)u) << 16;
    return v.f;
}
// packed 2x f32 -> bf16 pair (v_cvt_pk_bf16_f32 on gfx950)
__device__ __forceinline__ unsigned int pk2bf(float a, float b) {
    __hip_bfloat162 h = __float22bfloat162_rn(float2{a, b});
    union { __hip_bfloat162 h; unsigned int u; } v; v.h = h;
    return v.u;
}

// ---------------------------------------------------------------------------
// Merged prep kernel (R18): cvt_x (blocks 0..2047), tr_w (2048..2239),
// tr_wo (2240..2303). Branches are block-uniform; saves 2 kernel launches.
// ---------------------------------------------------------------------------
__global__ __launch_bounds__(256) void prep_kernel(
    const float* __restrict__ xin, unsigned short* __restrict__ xbf,
    const float* __restrict__ Wq, const float* __restrict__ Wk,
    const float* __restrict__ Wv, unsigned short* __restrict__ wtq,
    const float* __restrict__ Wo, unsigned short* __restrict__ wot)
{
    const int bid = blockIdx.x;
    const int t = threadIdx.x;

    if (bid < 2048) {
        // ---- cvt_x: x fp32 -> bf16, 8 elems/thread ----
        int gid = bid * 256 + t;
        float4 a = ((const float4*)xin)[gid * 2];
        float4 b = ((const float4*)xin)[gid * 2 + 1];
        uint4 u;
        u.x = pk2bf(a.x, a.y); u.y = pk2bf(a.z, a.w);
        u.z = pk2bf(b.x, b.y); u.w = pk2bf(b.z, b.w);
        ((uint4*)xbf)[gid] = u;
        return;
    }

    __shared__ float tile[64][65];
    int c = t & 63, r = t >> 6;

    if (bid < 2240) {
        // ---- tr_w: Wq/Wk/Wv [h][512][64] -> wtq [zh][64][512] bf16 ----
        int idx = bid - 2048;
        int k0 = (idx & 7) * 64;
        int zh = idx >> 3, z = zh >> 3, h = zh & 7;
        const float* src = (z == 0 ? Wq : z == 1 ? Wk : Wv)
                           + (size_t)h * DIM * HDIM;
        unsigned short* dst = wtq + (size_t)zh * HDIM * DIM;
        #pragma unroll
        for (int i = 0; i < 16; ++i)
            tile[r + 4 * i][c] = src[(size_t)(k0 + r + 4 * i) * HDIM + c];
        __syncthreads();
        #pragma unroll
        for (int i = 0; i < 16; ++i)
            dst[(size_t)(r + 4 * i) * DIM + k0 + c] = f2bf(tile[c][r + 4 * i]);
    } else {
        // ---- tr_wo: Wo [512][512] -> wot [512][512] bf16 transposed ----
        int idx = bid - 2240;
        int k0 = (idx & 7) * 64, e0 = (idx >> 3) * 64;
        #pragma unroll
        for (int i = 0; i < 16; ++i)
            tile[r + 4 * i][c] = Wo[(size_t)(k0 + r + 4 * i) * DIM + e0 + c];
        __syncthreads();
        #pragma unroll
        for (int i = 0; i < 16; ++i)
            wot[(size_t)(e0 + r + 4 * i) * DIM + k0 + c] = f2bf(tile[c][r + 4 * i]);
    }
}

// ---------------------------------------------------------------------------
// QKV projection, bf16 MFMA. R16 (kept): W B-frags staged through LDS,
// double-buffered 2x8KB with the proven XOR chunk swizzle + gload_lds path.
//   z=0: q_bf[h][n][e]  (scale*log2e folded)   z=1: k_bf[h][n][e]
//   z=2: vtp[h][e][pi(n)] = V^T with the PV sigma-permutation pre-applied.
// ---------------------------------------------------------------------------
__global__ __launch_bounds__(256) void qkv_mfma_kernel(
    const unsigned short* __restrict__ xbf,   // [N][512] bf16
    const unsigned short* __restrict__ wtq,   // [24][64][512] bf16
    const float* __restrict__ bq, const float* __restrict__ bk,
    const float* __restrict__ bv,
    unsigned short* __restrict__ q_bf, unsigned short* __restrict__ k_bf,
    unsigned short* __restrict__ vt_bf)
{
    const int zh = blockIdx.y, z = zh >> 3, h = zh & 7;
    const unsigned short* W = wtq + (size_t)zh * HDIM * DIM;
    const float* b = (z == 0 ? bq : z == 1 ? bk : bv) + h * HDIM;
    const int t = threadIdx.x, w = t >> 6, lane = t & 63;
    const int l15 = lane & 15, quad = lane >> 4;
    const int r0 = blockIdx.x * 128 + w * 32;

    __shared__ __align__(16) unsigned short Wlds[2][64 * 64];  // 2 x 8 KB

    const int koff0 = l15 * 64 + (quad ^ (l15 & 7)) * 8;
    const int koff1 = koff0 ^ 32;
    const int srow   = lane >> 3;
    const int schunk = (lane & 7) ^ srow;

    const unsigned short* Wp = W + (size_t)(16 * w + srow) * DIM + schunk * 8;

    __builtin_amdgcn_global_load_lds((const GLOBAL_AS void*)Wp,
        (LDS_AS void*)&Wlds[0][(16 * w) * 64], 16, 0, 0);
    __builtin_amdgcn_global_load_lds((const GLOBAL_AS void*)(Wp + (size_t)8 * DIM),
        (LDS_AS void*)&Wlds[0][(16 * w + 8) * 64], 16, 0, 0);
    Wp += 64;
    __syncthreads();
    int buf = 0;

    f32x4 O[2][4];
    #pragma unroll
    for (int mt = 0; mt < 2; ++mt)
        #pragma unroll
        for (int tn = 0; tn < 4; ++tn) O[mt][tn] = (f32x4){0.f, 0.f, 0.f, 0.f};

    for (int k0 = 0; k0 < DIM; k0 += 64) {
        if (k0 + 64 < DIM) {
            int nb = buf ^ 1;
            __builtin_amdgcn_global_load_lds((const GLOBAL_AS void*)Wp,
                (LDS_AS void*)&Wlds[nb][(16 * w) * 64], 16, 0, 0);
            __builtin_amdgcn_global_load_lds(
                (const GLOBAL_AS void*)(Wp + (size_t)8 * DIM),
                (LDS_AS void*)&Wlds[nb][(16 * w + 8) * 64], 16, 0, 0);
            Wp += 64;
        }

        bf16x8 af[2][2];
        #pragma unroll
        for (int mt = 0; mt < 2; ++mt)
            #pragma unroll
            for (int kc = 0; kc < 2; ++kc)
                af[mt][kc] = *(const bf16x8*)
                    &xbf[(size_t)(r0 + 16 * mt + l15) * DIM + k0 + quad * 8 + 32 * kc];

        bf16x8 bf[4][2];
        #pragma unroll
        for (int tn = 0; tn < 4; ++tn) {
            bf[tn][0] = *(const bf16x8*)&Wlds[buf][1024 * tn + koff0];
            bf[tn][1] = *(const bf16x8*)&Wlds[buf][1024 * tn + koff1];
        }

        #pragma unroll
        for (int mt = 0; mt < 2; ++mt)
            #pragma unroll
            for (int tn = 0; tn < 4; ++tn) {
                O[mt][tn] = __builtin_amdgcn_mfma_f32_16x16x32_bf16(
                    af[mt][0], bf[tn][0], O[mt][tn], 0, 0, 0);
                O[mt][tn] = __builtin_amdgcn_mfma_f32_16x16x32_bf16(
                    af[mt][1], bf[tn][1], O[mt][tn], 0, 0, 0);
            }

        __syncthreads();
        buf ^= 1;
    }

    if (z < 2) {
        unsigned short* outp = (z == 0 ? q_bf : k_bf) + (size_t)h * NPTS * HDIM;
        const float sc = (z == 0) ? 0.18033688011112042f : 1.0f;  // 0.125*log2e | 1
        #pragma unroll
        for (int mt = 0; mt < 2; ++mt)
            #pragma unroll
            for (int tn = 0; tn < 4; ++tn) {
                int e = l15 + 16 * tn;
                float be = b[e];
                #pragma unroll
                for (int r = 0; r < 4; ++r) {
                    int n = r0 + 16 * mt + quad * 4 + r;
                    outp[(size_t)n * HDIM + e] = f2bf((O[mt][tn][r] + be) * sc);
                }
            }
    } else {
        unsigned short* vt = vt_bf + (size_t)h * HDIM * NPTS;
        #pragma unroll
        for (int mt = 0; mt < 2; ++mt)
            #pragma unroll
            for (int tn = 0; tn < 4; ++tn) {
                int e = l15 + 16 * tn;
                float be = b[e];
                uint2 pk;
                pk.x = pk2bf(O[mt][tn][0] + be, O[mt][tn][1] + be);
                pk.y = pk2bf(O[mt][tn][2] + be, O[mt][tn][3] + be);
                // sigma-permuted position within this 32-row block
                *(uint2*)&vt[(size_t)e * NPTS + r0 + quad * 8 + mt * 4] = pk;
            }
    }
}

// ---------------------------------------------------------------------------
// MFMA flash attention, R19: R14b wave structure (proven), k-split 4.
// R18 counters: MfmaUtil 38 + VALUBusy 54 are DIFFERENT pipes running near-
// serially (sum ~92%, neither saturated). 512 blocks = 2 barrier domains/CU
// was the limit. Grid (32,8,4) = 1024 blocks x 256 thr = 16 waves/CU = 4
// independent domains (LDS 4x32=128<=160, VGPR 112 -> 4 waves/SIMD).
// Per-wave inner loop byte-identical; key range 2048 (32 iters).
// op partial for ks=2 aliases xbf (dead after qkv); ks=3 in fresh ws.
// Sentinel: attn WRITE_SIZE ~33.8 MB now EXPECTED (4 partials), VGPR 112.
// ---------------------------------------------------------------------------
#define STAGE_TILE(B)                                                         \
    do {                                                                      \
        __builtin_amdgcn_global_load_lds((const GLOBAL_AS void*)Kp,           \
            (LDS_AS void*)&Klds[B][(16 * w) * 64], 16, 0, 0);                 \
        __builtin_amdgcn_global_load_lds((const GLOBAL_AS void*)(Kp + 8 * HDIM), \
            (LDS_AS void*)&Klds[B][(16 * w + 8) * 64], 16, 0, 0);             \
        __builtin_amdgcn_global_load_lds((const GLOBAL_AS void*)Vp0,          \
            (LDS_AS void*)&Vlds[B][(16 * w) * 64], 16, 0, 0);                 \
        __builtin_amdgcn_global_load_lds((const GLOBAL_AS void*)Vp1,          \
            (LDS_AS void*)&Vlds[B][(16 * w + 8) * 64], 16, 0, 0);             \
        Kp += 64 * HDIM; Vp0 += 64; Vp1 += 64;                                \
    } while (0)

__global__ __launch_bounds__(256) void attn_kernel(
    const unsigned short* __restrict__ qg,   // [H][N][64] bf16, pre-scaled
    const unsigned short* __restrict__ kg,   // [H][N][64] bf16
    const unsigned short* __restrict__ vtg,  // [H][64][N] bf16, sigma-permuted
    unsigned short* __restrict__ opA,        // ks=0 partial [N][DIM] bf16
    unsigned short* __restrict__ opB,        // ks=1
    unsigned short* __restrict__ opC,        // ks=2 (aliases xbf)
    unsigned short* __restrict__ opD,        // ks=3
    float* __restrict__ lpart)               // [4][H][N] fp32
{
    const int h  = blockIdx.y;
    const int ks = blockIdx.z;
    const int q0 = blockIdx.x * 256;
    const int kbase = ks * (NPTS / NSPLIT);
    const unsigned short* Q  = qg  + (size_t)h * NPTS * HDIM;
    const unsigned short* K  = kg  + (size_t)h * NPTS * HDIM;
    const unsigned short* Vt = vtg + (size_t)h * HDIM * NPTS;
    unsigned short* op = (ks == 0) ? opA : (ks == 1) ? opB
                       : (ks == 2) ? opC : opD;
    float* lp = lpart + (size_t)(ks * NHEAD + h) * NPTS;

    __shared__ __align__(16) unsigned short Klds[2][64 * 64];  // 16 KB
    __shared__ __align__(16) unsigned short Vlds[2][64 * 64];  // 16 KB

    const int t    = threadIdx.x;
    const int w    = t >> 6;
    const int lane = t & 63;
    const int l15  = lane & 15;
    const int quad = lane >> 4;

    const int koff0 = l15 * 64 + (quad ^ (l15 & 7)) * 8;
    const int koff1 = koff0 ^ 32;

    const int srow   = lane >> 3;
    const int schunk = (lane & 7) ^ srow;

    // Q B-frags: 4 m-tiles of 16 rows -> 64 q-rows per wave
    bf16x8 qf[4][2];
    #pragma unroll
    for (int m = 0; m < 4; ++m)
        #pragma unroll
        for (int kc = 0; kc < 2; ++kc)
            qf[m][kc] = *(const bf16x8*)
                &Q[(size_t)(q0 + 64 * w + 16 * m + l15) * HDIM + quad * 8 + 32 * kc];

    // all-ones bf16 A-frag for the row-sum MFMA (0x3F80 == bf16 1.0)
    const bf16x8 ones = {(short)0x3F80, (short)0x3F80, (short)0x3F80,
                         (short)0x3F80, (short)0x3F80, (short)0x3F80,
                         (short)0x3F80, (short)0x3F80};
    // persistent zero C-in: seeds each st accumulation without fresh movs
    const f32x4 Z0 = (f32x4){0.f, 0.f, 0.f, 0.f};

    // O^T accumulators [te][m]: row=quad*4+r -> e, col=l15 -> qrow
    f32x4 OT[4][4];
    f32x4 Lacc[4];
    #pragma unroll
    for (int te = 0; te < 4; ++te)
        #pragma unroll
        for (int m = 0; m < 4; ++m) OT[te][m] = (f32x4){0.f, 0.f, 0.f, 0.f};
    #pragma unroll
    for (int m = 0; m < 4; ++m) Lacc[m] = (f32x4){0.f, 0.f, 0.f, 0.f};

    // running staging pointers (advanced by constant strides inside STAGE_TILE)
    const unsigned short* Kp  = K  + (size_t)(kbase + 16 * w + srow) * HDIM
                                   + schunk * 8;
    const unsigned short* Vp0 = Vt + (size_t)(16 * w + srow) * NPTS
                                   + kbase + schunk * 8;
    const unsigned short* Vp1 = Vp0 + (size_t)8 * NPTS;

    STAGE_TILE(0);
    __syncthreads();
    int buf = 0;

    for (int kt = 0; kt < NPTS / NSPLIT; kt += 64) {
        // issue next stage first: a full body of latency cover before the
        // barrier's vmcnt(0) drain
        if (kt + 64 < NPTS / NSPLIT) {
            const int nxt = buf ^ 1;
            if (nxt) STAGE_TILE(1); else STAGE_TILE(0);
        }

        bf16x8 pt[2][4];

        // ---- subphase kb=0: keys 0..31 of the tile (kn slots 0,1) ----
        {
            bf16x8 kf[2][2];
            #pragma unroll
            for (int kn = 0; kn < 2; ++kn) {
                kf[kn][0] = *(const bf16x8*)&Klds[buf][1024 * kn + koff0];
                kf[kn][1] = *(const bf16x8*)&Klds[buf][1024 * kn + koff1];
            }
            f32x4 st[2][4];
            #pragma unroll
            for (int kn = 0; kn < 2; ++kn)
                #pragma unroll
                for (int m = 0; m < 4; ++m) {
                    st[kn][m] = __builtin_amdgcn_mfma_f32_16x16x32_bf16(
                        kf[kn][0], qf[m][0], Z0, 0, 0, 0);
                    st[kn][m] = __builtin_amdgcn_mfma_f32_16x16x32_bf16(
                        kf[kn][1], qf[m][1], st[kn][m], 0, 0, 0);
                }
            #pragma unroll
            for (int m = 0; m < 4; ++m) {
                float e0 = EXP2F(st[0][m][0]);
                float e1 = EXP2F(st[0][m][1]);
                float e2 = EXP2F(st[0][m][2]);
                float e3 = EXP2F(st[0][m][3]);
                float e4 = EXP2F(st[1][m][0]);
                float e5 = EXP2F(st[1][m][1]);
                float e6 = EXP2F(st[1][m][2]);
                float e7 = EXP2F(st[1][m][3]);
                union { uint4 u; bf16x8 v; } uu;
                uu.u.x = pk2bf(e0, e1);
                uu.u.y = pk2bf(e2, e3);
                uu.u.z = pk2bf(e4, e5);
                uu.u.w = pk2bf(e6, e7);
                pt[0][m] = uu.v;
            }
        }

        // V A-frags te=0,1 issued here: LDS reads drain under the kb=1 QK
        // MFMA burst (R13 overlap lesson)
        bf16x8 vf0[2][2];
        #pragma unroll
        for (int te = 0; te < 2; ++te) {
            vf0[te][0] = *(const bf16x8*)&Vlds[buf][1024 * te + koff0];
            vf0[te][1] = *(const bf16x8*)&Vlds[buf][1024 * te + koff1];
        }

        // ---- subphase kb=1: keys 32..63 of the tile (kn slots 2,3) ----
        {
            bf16x8 kf[2][2];
            #pragma unroll
            for (int kn = 0; kn < 2; ++kn) {
                kf[kn][0] = *(const bf16x8*)&Klds[buf][1024 * (kn + 2) + koff0];
                kf[kn][1] = *(const bf16x8*)&Klds[buf][1024 * (kn + 2) + koff1];
            }
            f32x4 st[2][4];
            #pragma unroll
            for (int kn = 0; kn < 2; ++kn)
                #pragma unroll
                for (int m = 0; m < 4; ++m) {
                    st[kn][m] = __builtin_amdgcn_mfma_f32_16x16x32_bf16(
                        kf[kn][0], qf[m][0], Z0, 0, 0, 0);
                    st[kn][m] = __builtin_amdgcn_mfma_f32_16x16x32_bf16(
                        kf[kn][1], qf[m][1], st[kn][m], 0, 0, 0);
                }
            #pragma unroll
            for (int m = 0; m < 4; ++m) {
                float e0 = EXP2F(st[0][m][0]);
                float e1 = EXP2F(st[0][m][1]);
                float e2 = EXP2F(st[0][m][2]);
                float e3 = EXP2F(st[0][m][3]);
                float e4 = EXP2F(st[1][m][0]);
                float e5 = EXP2F(st[1][m][1]);
                float e6 = EXP2F(st[1][m][2]);
                float e7 = EXP2F(st[1][m][3]);
                union { uint4 u; bf16x8 v; } uu;
                uu.u.x = pk2bf(e0, e1);
                uu.u.y = pk2bf(e2, e3);
                uu.u.z = pk2bf(e4, e5);
                uu.u.w = pk2bf(e6, e7);
                pt[1][m] = uu.v;
            }
        }

        // V A-frags te=2,3: drain under Lacc + PV-te01 MFMAs
        bf16x8 vf1[2][2];
        #pragma unroll
        for (int te = 0; te < 2; ++te) {
            vf1[te][0] = *(const bf16x8*)&Vlds[buf][1024 * (te + 2) + koff0];
            vf1[te][1] = *(const bf16x8*)&Vlds[buf][1024 * (te + 2) + koff1];
        }

        // row-sum in the matrix pipe: Lacc[m] += ones x pt (all rows equal l)
        #pragma unroll
        for (int kb = 0; kb < 2; ++kb)
            #pragma unroll
            for (int m = 0; m < 4; ++m)
                Lacc[m] = __builtin_amdgcn_mfma_f32_16x16x32_bf16(
                    ones, pt[kb][m], Lacc[m], 0, 0, 0);

        // O^T += V^T P^T  (pure register path); te01 first (vf0 ready),
        // te23 last (vf1 reads covered by the MFMAs above)
        #pragma unroll
        for (int te = 0; te < 2; ++te)
            #pragma unroll
            for (int m = 0; m < 4; ++m) {
                OT[te][m] = __builtin_amdgcn_mfma_f32_16x16x32_bf16(
                    vf0[te][0], pt[0][m], OT[te][m], 0, 0, 0);
                OT[te][m] = __builtin_amdgcn_mfma_f32_16x16x32_bf16(
                    vf0[te][1], pt[1][m], OT[te][m], 0, 0, 0);
            }
        #pragma unroll
        for (int te = 0; te < 2; ++te)
            #pragma unroll
            for (int m = 0; m < 4; ++m) {
                OT[te + 2][m] = __builtin_amdgcn_mfma_f32_16x16x32_bf16(
                    vf1[te][0], pt[0][m], OT[te + 2][m], 0, 0, 0);
                OT[te + 2][m] = __builtin_amdgcn_mfma_f32_16x16x32_bf16(
                    vf1[te][1], pt[1][m], OT[te + 2][m], 0, 0, 0);
            }

        __syncthreads();   // Klds/Vlds[buf] reads done; next stage visible
        buf ^= 1;
    }

    // epilogue: l comes straight out of Lacc (all components/quads equal);
    // write unnormalized O^T packed
    #pragma unroll
    for (int m = 0; m < 4; ++m) {
        int n = q0 + 64 * w + 16 * m + l15;
        if (quad == 0) lp[n] = Lacc[m][0];
        #pragma unroll
        for (int te = 0; te < 4; ++te) {
            uint2 pk;
            pk.x = pk2bf(OT[te][m][0], OT[te][m][1]);
            pk.y = pk2bf(OT[te][m][2], OT[te][m][3]);
            *(uint2*)&op[(size_t)n * DIM + h * HDIM + 16 * te + quad * 4] = pk;
        }
    }
}

// ---------------------------------------------------------------------------
// Output projection + 4-way k-split merge fused (R19). Full wot c0-tile
// (64 KB) staged once (R18); per k-step: 16 af loads (4 partials), 8-chain
// MFMA per (mt,tn), then O += Os * inv with inv = 1/(l0+l1+l2+l3).
// ---------------------------------------------------------------------------
__global__ __launch_bounds__(256) void out_mfma_kernel(
    const unsigned short* __restrict__ op0,
    const unsigned short* __restrict__ op1,
    const unsigned short* __restrict__ op2,
    const unsigned short* __restrict__ op3,
    const float* __restrict__ lpart,          // [4][H][N] fp32
    const unsigned short* __restrict__ wot,   // [512][512] bf16 [e_out][k]
    const float* __restrict__ bo, const float* __restrict__ x,
    float* __restrict__ outp)
{
    const int t = threadIdx.x, w = t >> 6, lane = t & 63;
    const int l15 = lane & 15, quad = lane >> 4;
    const int r0 = blockIdx.x * 128 + w * 32;
    const int c0 = blockIdx.y * 64;

    __shared__ __align__(16) unsigned short Wlds[8][64 * 64];  // 64 KB

    const int koff0 = l15 * 64 + (quad ^ (l15 & 7)) * 8;
    const int koff1 = koff0 ^ 32;
    const int srow   = lane >> 3;
    const int schunk = (lane & 7) ^ srow;

    const f32x4 Z0 = (f32x4){0.f, 0.f, 0.f, 0.f};

    // stage the whole [c0..c0+63] x [0..511] wot tile: 8 regions of 64x64
    {
        const unsigned short* Wb = wot + (size_t)(c0 + 16 * w + srow) * DIM
                                       + schunk * 8;
        #pragma unroll
        for (int kc = 0; kc < 8; ++kc) {
            __builtin_amdgcn_global_load_lds(
                (const GLOBAL_AS void*)(Wb + kc * 64),
                (LDS_AS void*)&Wlds[kc][(16 * w) * 64], 16, 0, 0);
            __builtin_amdgcn_global_load_lds(
                (const GLOBAL_AS void*)(Wb + (size_t)8 * DIM + kc * 64),
                (LDS_AS void*)&Wlds[kc][(16 * w + 8) * 64], 16, 0, 0);
        }
    }
    __syncthreads();

    f32x4 O[2][4];
    #pragma unroll
    for (int mt = 0; mt < 2; ++mt)
        #pragma unroll
        for (int tn = 0; tn < 4; ++tn) O[mt][tn] = (f32x4){0.f, 0.f, 0.f, 0.f};

    #pragma unroll
    for (int h = 0; h < 8; ++h) {
        const int k0 = h * 64;

        // unnormalized A-frags from all four k-split partials
        bf16x8 af0[2][2], af1[2][2], af2[2][2], af3[2][2];
        #pragma unroll
        for (int mt = 0; mt < 2; ++mt)
            #pragma unroll
            for (int kc = 0; kc < 2; ++kc) {
                size_t idx = (size_t)(r0 + 16 * mt + l15) * DIM
                             + k0 + quad * 8 + 32 * kc;
                af0[mt][kc] = *(const bf16x8*)&op0[idx];
                af1[mt][kc] = *(const bf16x8*)&op1[idx];
                af2[mt][kc] = *(const bf16x8*)&op2[idx];
                af3[mt][kc] = *(const bf16x8*)&op3[idx];
            }

        // inv per (mt, r): 1 / sum of 4 partial l's
        float inv0[4], inv1[4];
        {
            const float* l0 = lpart + (size_t)(0 * NHEAD + h) * NPTS;
            const float* l1 = lpart + (size_t)(1 * NHEAD + h) * NPTS;
            const float* l2 = lpart + (size_t)(2 * NHEAD + h) * NPTS;
            const float* l3 = lpart + (size_t)(3 * NHEAD + h) * NPTS;
            const float4 a0 = *(const float4*)&l0[r0 + quad * 4];
            const float4 b0 = *(const float4*)&l1[r0 + quad * 4];
            const float4 c0v = *(const float4*)&l2[r0 + quad * 4];
            const float4 d0 = *(const float4*)&l3[r0 + quad * 4];
            const float4 a1 = *(const float4*)&l0[r0 + 16 + quad * 4];
            const float4 b1 = *(const float4*)&l1[r0 + 16 + quad * 4];
            const float4 c1 = *(const float4*)&l2[r0 + 16 + quad * 4];
            const float4 d1 = *(const float4*)&l3[r0 + 16 + quad * 4];
            inv0[0] = 1.0f / (a0.x + b0.x + c0v.x + d0.x);
            inv0[1] = 1.0f / (a0.y + b0.y + c0v.y + d0.y);
            inv0[2] = 1.0f / (a0.z + b0.z + c0v.z + d0.z);
            inv0[3] = 1.0f / (a0.w + b0.w + c0v.w + d0.w);
            inv1[0] = 1.0f / (a1.x + b1.x + c1.x + d1.x);
            inv1[1] = 1.0f / (a1.y + b1.y + c1.y + d1.y);
            inv1[2] = 1.0f / (a1.z + b1.z + c1.z + d1.z);
            inv1[3] = 1.0f / (a1.w + b1.w + c1.w + d1.w);
        }

        // bf from LDS region h
        bf16x8 bf[4][2];
        #pragma unroll
        for (int tn = 0; tn < 4; ++tn) {
            bf[tn][0] = *(const bf16x8*)&Wlds[h][1024 * tn + koff0];
            bf[tn][1] = *(const bf16x8*)&Wlds[h][1024 * tn + koff1];
        }

        // per-k-step partial: Os = (af0+af1+af2+af3) x bf  (8 chained MFMAs)
        #pragma unroll
        for (int mt = 0; mt < 2; ++mt) {
            const float* inv = (mt == 0) ? inv0 : inv1;
            #pragma unroll
            for (int tn = 0; tn < 4; ++tn) {
                f32x4 Os;
                Os = __builtin_amdgcn_mfma_f32_16x16x32_bf16(
                    af0[mt][0], bf[tn][0], Z0, 0, 0, 0);
                Os = __builtin_amdgcn_mfma_f32_16x16x32_bf16(
                    af0[mt][1], bf[tn][1], Os, 0, 0, 0);
                Os = __builtin_amdgcn_mfma_f32_16x16x32_bf16(
                    af1[mt][0], bf[tn][0], Os, 0, 0, 0);
                Os = __builtin_amdgcn_mfma_f32_16x16x32_bf16(
                    af1[mt][1], bf[tn][1], Os, 0, 0, 0);
                Os = __builtin_amdgcn_mfma_f32_16x16x32_bf16(
                    af2[mt][0], bf[tn][0], Os, 0, 0, 0);
                Os = __builtin_amdgcn_mfma_f32_16x16x32_bf16(
                    af2[mt][1], bf[tn][1], Os, 0, 0, 0);
                Os = __builtin_amdgcn_mfma_f32_16x16x32_bf16(
                    af3[mt][0], bf[tn][0], Os, 0, 0, 0);
                Os = __builtin_amdgcn_mfma_f32_16x16x32_bf16(
                    af3[mt][1], bf[tn][1], Os, 0, 0, 0);
                #pragma unroll
                for (int r = 0; r < 4; ++r)
                    O[mt][tn][r] += Os[r] * inv[r];
            }
        }
    }

    #pragma unroll
    for (int mt = 0; mt < 2; ++mt)
        #pragma unroll
        for (int tn = 0; tn < 4; ++tn) {
            int e = c0 + l15 + 16 * tn;
            float be = bo[e];
            #pragma unroll
            for (int r = 0; r < 4; ++r) {
                int n = r0 + 16 * mt + quad * 4 + r;
                outp[(size_t)n * DIM + e] = O[mt][tn][r] + be + x[(size_t)n * DIM + e];
            }
        }
}

extern "C" void kernel_launch(void* const* d_in, const int* in_sizes, int n_in,
                              void* d_out, int out_size, void* d_ws, size_t ws_size,
                              hipStream_t stream) {
    const float* x  = (const float*)d_in[0];
    const float* Wq = (const float*)d_in[1];
    const float* bq = (const float*)d_in[2];
    const float* Wk = (const float*)d_in[3];
    const float* bk = (const float*)d_in[4];
    const float* Wv = (const float*)d_in[5];
    const float* bv = (const float*)d_in[6];
    const float* Wo = (const float*)d_in[7];
    const float* bo = (const float*)d_in[8];
    float* out = (float*)d_out;

    const size_t per = (size_t)NHEAD * NPTS * HDIM;            // 4M elems
    unsigned short* xbf   = (unsigned short*)d_ws;             //  8 MB [op2 after qkv]
    unsigned short* wtq   = xbf + (size_t)NPTS * DIM;          //  1.5 MB
    unsigned short* wot   = wtq + (size_t)24 * HDIM * DIM;     //  0.5 MB
    unsigned short* q_bf  = wot + (size_t)DIM * DIM;           //  8 MB
    unsigned short* k_bf  = q_bf + per;                        //  8 MB
    unsigned short* vt_bf = k_bf + per;                        //  8 MB
    unsigned short* op0   = vt_bf + per;                       //  8 MB
    unsigned short* op1   = op0 + (size_t)NPTS * DIM;          //  8 MB
    float*          lpart = (float*)(op1 + (size_t)NPTS * DIM); //  1 MB (4 splits)
    unsigned short* op3   = (unsigned short*)(lpart
                              + (size_t)NSPLIT * NHEAD * NPTS); //  8 MB
    unsigned short* op2   = xbf;   // alias: xbf dead after qkv_mfma
    // total ws: ~59 MB

    prep_kernel<<<dim3(2304), 256, 0, stream>>>(
        x, xbf, Wq, Wk, Wv, wtq, Wo, wot);
    qkv_mfma_kernel<<<dim3(NPTS / 128, 24), 256, 0, stream>>>(
        xbf, wtq, bq, bk, bv, q_bf, k_bf, vt_bf);
    attn_kernel<<<dim3(NPTS / 256, NHEAD, NSPLIT), 256, 0, stream>>>(
        q_bf, k_bf, vt_bf, op0, op1, op2, op3, lpart);
    out_mfma_kernel<<<dim3(NPTS / 128, DIM / 64), 256, 0, stream>>>(
        op0, op1, op2, op3, lpart, wot, bo, x, out);
}

// Round 16
// 279.528 us; speedup vs baseline: 1.0760x; 1.0760x over previous
//
#include <hip/hip_runtime.h>
#include <hip/hip_bf16.h>

#define NPTS 8192
#define DIM  512
#define NHEAD 8
#define HDIM 64

typedef short bf16x8 __attribute__((ext_vector_type(8)));   // 8 bf16 = 4 VGPRs
typedef float f32x4  __attribute__((ext_vector_type(4)));   // MFMA C/D

#define GLOBAL_AS __attribute__((address_space(1)))
#define LDS_AS    __attribute__((address_space(3)))

#if __has_builtin(__builtin_amdgcn_exp2f)
#define EXP2F(x) __builtin_amdgcn_exp2f(x)
#else
#define EXP2F(x) __expf((x) * 0.6931471805599453f)
#endif

// fp32 -> bf16 round-nearest-even (scalar)
__device__ __forceinline__ unsigned short f2bf(float f) {
    union { float f; unsigned int u; } v; v.f = f;
    unsigned int r = v.u + 0x7FFFu + ((v.u >> 16) & 1u);
    return (unsigned short)(r >> 16);
}
__device__ __forceinline__ float bf2f(unsigned short u) {
    union { unsigned int i; float f; } v; v.i = ((unsigned int)u) << 16;
    return v.f;
}
// packed 2x f32 -> bf16 pair (v_cvt_pk_bf16_f32 on gfx950)
__device__ __forceinline__ unsigned int pk2bf(float a, float b) {
    __hip_bfloat162 h = __float22bfloat162_rn(float2{a, b});
    union { __hip_bfloat162 h; unsigned int u; } v; v.h = h;
    return v.u;
}

// ---------------------------------------------------------------------------
// Merged prep kernel (R18): cvt_x (blocks 0..2047), tr_w (2048..2239),
// tr_wo (2240..2303). Branches are block-uniform; saves 2 kernel launches.
// ---------------------------------------------------------------------------
__global__ __launch_bounds__(256) void prep_kernel(
    const float* __restrict__ xin, unsigned short* __restrict__ xbf,
    const float* __restrict__ Wq, const float* __restrict__ Wk,
    const float* __restrict__ Wv, unsigned short* __restrict__ wtq,
    const float* __restrict__ Wo, unsigned short* __restrict__ wot)
{
    const int bid = blockIdx.x;
    const int t = threadIdx.x;

    if (bid < 2048) {
        // ---- cvt_x: x fp32 -> bf16, 8 elems/thread ----
        int gid = bid * 256 + t;
        float4 a = ((const float4*)xin)[gid * 2];
        float4 b = ((const float4*)xin)[gid * 2 + 1];
        uint4 u;
        u.x = pk2bf(a.x, a.y); u.y = pk2bf(a.z, a.w);
        u.z = pk2bf(b.x, b.y); u.w = pk2bf(b.z, b.w);
        ((uint4*)xbf)[gid] = u;
        return;
    }

    __shared__ float tile[64][65];
    int c = t & 63, r = t >> 6;

    if (bid < 2240) {
        // ---- tr_w: Wq/Wk/Wv [h][512][64] -> wtq [zh][64][512] bf16 ----
        int idx = bid - 2048;
        int k0 = (idx & 7) * 64;
        int zh = idx >> 3, z = zh >> 3, h = zh & 7;
        const float* src = (z == 0 ? Wq : z == 1 ? Wk : Wv)
                           + (size_t)h * DIM * HDIM;
        unsigned short* dst = wtq + (size_t)zh * HDIM * DIM;
        #pragma unroll
        for (int i = 0; i < 16; ++i)
            tile[r + 4 * i][c] = src[(size_t)(k0 + r + 4 * i) * HDIM + c];
        __syncthreads();
        #pragma unroll
        for (int i = 0; i < 16; ++i)
            dst[(size_t)(r + 4 * i) * DIM + k0 + c] = f2bf(tile[c][r + 4 * i]);
    } else {
        // ---- tr_wo: Wo [512][512] -> wot [512][512] bf16 transposed ----
        int idx = bid - 2240;
        int k0 = (idx & 7) * 64, e0 = (idx >> 3) * 64;
        #pragma unroll
        for (int i = 0; i < 16; ++i)
            tile[r + 4 * i][c] = Wo[(size_t)(k0 + r + 4 * i) * DIM + e0 + c];
        __syncthreads();
        #pragma unroll
        for (int i = 0; i < 16; ++i)
            wot[(size_t)(e0 + r + 4 * i) * DIM + k0 + c] = f2bf(tile[c][r + 4 * i]);
    }
}

// ---------------------------------------------------------------------------
// QKV projection, bf16 MFMA. R16 (kept): W B-frags staged through LDS,
// double-buffered 2x8KB with the proven XOR chunk swizzle + gload_lds path.
//   z=0: q_bf[h][n][e]  (scale*log2e folded)   z=1: k_bf[h][n][e]
//   z=2: vtp[h][e][pi(n)] = V^T with the PV sigma-permutation pre-applied.
// ---------------------------------------------------------------------------
__global__ __launch_bounds__(256) void qkv_mfma_kernel(
    const unsigned short* __restrict__ xbf,   // [N][512] bf16
    const unsigned short* __restrict__ wtq,   // [24][64][512] bf16
    const float* __restrict__ bq, const float* __restrict__ bk,
    const float* __restrict__ bv,
    unsigned short* __restrict__ q_bf, unsigned short* __restrict__ k_bf,
    unsigned short* __restrict__ vt_bf)
{
    const int zh = blockIdx.y, z = zh >> 3, h = zh & 7;
    const unsigned short* W = wtq + (size_t)zh * HDIM * DIM;
    const float* b = (z == 0 ? bq : z == 1 ? bk : bv) + h * HDIM;
    const int t = threadIdx.x, w = t >> 6, lane = t & 63;
    const int l15 = lane & 15, quad = lane >> 4;
    const int r0 = blockIdx.x * 128 + w * 32;

    __shared__ __align__(16) unsigned short Wlds[2][64 * 64];  // 2 x 8 KB

    const int koff0 = l15 * 64 + (quad ^ (l15 & 7)) * 8;
    const int koff1 = koff0 ^ 32;
    const int srow   = lane >> 3;
    const int schunk = (lane & 7) ^ srow;

    const unsigned short* Wp = W + (size_t)(16 * w + srow) * DIM + schunk * 8;

    __builtin_amdgcn_global_load_lds((const GLOBAL_AS void*)Wp,
        (LDS_AS void*)&Wlds[0][(16 * w) * 64], 16, 0, 0);
    __builtin_amdgcn_global_load_lds((const GLOBAL_AS void*)(Wp + (size_t)8 * DIM),
        (LDS_AS void*)&Wlds[0][(16 * w + 8) * 64], 16, 0, 0);
    Wp += 64;
    __syncthreads();
    int buf = 0;

    f32x4 O[2][4];
    #pragma unroll
    for (int mt = 0; mt < 2; ++mt)
        #pragma unroll
        for (int tn = 0; tn < 4; ++tn) O[mt][tn] = (f32x4){0.f, 0.f, 0.f, 0.f};

    for (int k0 = 0; k0 < DIM; k0 += 64) {
        if (k0 + 64 < DIM) {
            int nb = buf ^ 1;
            __builtin_amdgcn_global_load_lds((const GLOBAL_AS void*)Wp,
                (LDS_AS void*)&Wlds[nb][(16 * w) * 64], 16, 0, 0);
            __builtin_amdgcn_global_load_lds(
                (const GLOBAL_AS void*)(Wp + (size_t)8 * DIM),
                (LDS_AS void*)&Wlds[nb][(16 * w + 8) * 64], 16, 0, 0);
            Wp += 64;
        }

        bf16x8 af[2][2];
        #pragma unroll
        for (int mt = 0; mt < 2; ++mt)
            #pragma unroll
            for (int kc = 0; kc < 2; ++kc)
                af[mt][kc] = *(const bf16x8*)
                    &xbf[(size_t)(r0 + 16 * mt + l15) * DIM + k0 + quad * 8 + 32 * kc];

        bf16x8 bf[4][2];
        #pragma unroll
        for (int tn = 0; tn < 4; ++tn) {
            bf[tn][0] = *(const bf16x8*)&Wlds[buf][1024 * tn + koff0];
            bf[tn][1] = *(const bf16x8*)&Wlds[buf][1024 * tn + koff1];
        }

        #pragma unroll
        for (int mt = 0; mt < 2; ++mt)
            #pragma unroll
            for (int tn = 0; tn < 4; ++tn) {
                O[mt][tn] = __builtin_amdgcn_mfma_f32_16x16x32_bf16(
                    af[mt][0], bf[tn][0], O[mt][tn], 0, 0, 0);
                O[mt][tn] = __builtin_amdgcn_mfma_f32_16x16x32_bf16(
                    af[mt][1], bf[tn][1], O[mt][tn], 0, 0, 0);
            }

        __syncthreads();
        buf ^= 1;
    }

    if (z < 2) {
        unsigned short* outp = (z == 0 ? q_bf : k_bf) + (size_t)h * NPTS * HDIM;
        const float sc = (z == 0) ? 0.18033688011112042f : 1.0f;  // 0.125*log2e | 1
        #pragma unroll
        for (int mt = 0; mt < 2; ++mt)
            #pragma unroll
            for (int tn = 0; tn < 4; ++tn) {
                int e = l15 + 16 * tn;
                float be = b[e];
                #pragma unroll
                for (int r = 0; r < 4; ++r) {
                    int n = r0 + 16 * mt + quad * 4 + r;
                    outp[(size_t)n * HDIM + e] = f2bf((O[mt][tn][r] + be) * sc);
                }
            }
    } else {
        unsigned short* vt = vt_bf + (size_t)h * HDIM * NPTS;
        #pragma unroll
        for (int mt = 0; mt < 2; ++mt)
            #pragma unroll
            for (int tn = 0; tn < 4; ++tn) {
                int e = l15 + 16 * tn;
                float be = b[e];
                uint2 pk;
                pk.x = pk2bf(O[mt][tn][0] + be, O[mt][tn][1] + be);
                pk.y = pk2bf(O[mt][tn][2] + be, O[mt][tn][3] + be);
                // sigma-permuted position within this 32-row block
                *(uint2*)&vt[(size_t)e * NPTS + r0 + quad * 8 + mt * 4] = pk;
            }
    }
}

// ---------------------------------------------------------------------------
// MFMA flash attention, R20: R14b structure (session-best) + T5 s_setprio
// around the three MFMA clusters. R19 post-mortem: k-split 4 was a null
// (attn flat, occupancy 17.9->19.4 not 30+; out_mfma merge cost more than
// saved) -- attn is NOT wave-starved; the limit is the intra-wave
// QK->softmax->PV critical path with ~97% issue saturation. setprio(1)
// during MFMA clusters biases the CU scheduler so the OTHER resident
// block's waves fill VALU gaps (catalog T5: +4-7% on attn with independent
// blocks at different phases; our 2 blocks/CU are barrier-independent).
// k-split back to 2. Sentinels: VGPR 112, WRITE 16.9 MB.
// ---------------------------------------------------------------------------
#define STAGE_TILE(B)                                                         \
    do {                                                                      \
        __builtin_amdgcn_global_load_lds((const GLOBAL_AS void*)Kp,           \
            (LDS_AS void*)&Klds[B][(16 * w) * 64], 16, 0, 0);                 \
        __builtin_amdgcn_global_load_lds((const GLOBAL_AS void*)(Kp + 8 * HDIM), \
            (LDS_AS void*)&Klds[B][(16 * w + 8) * 64], 16, 0, 0);             \
        __builtin_amdgcn_global_load_lds((const GLOBAL_AS void*)Vp0,          \
            (LDS_AS void*)&Vlds[B][(16 * w) * 64], 16, 0, 0);                 \
        __builtin_amdgcn_global_load_lds((const GLOBAL_AS void*)Vp1,          \
            (LDS_AS void*)&Vlds[B][(16 * w + 8) * 64], 16, 0, 0);             \
        Kp += 64 * HDIM; Vp0 += 64; Vp1 += 64;                                \
    } while (0)

__global__ __launch_bounds__(256) void attn_kernel(
    const unsigned short* __restrict__ qg,   // [H][N][64] bf16, pre-scaled
    const unsigned short* __restrict__ kg,   // [H][N][64] bf16
    const unsigned short* __restrict__ vtg,  // [H][64][N] bf16, sigma-permuted
    unsigned short* __restrict__ opart,      // [2][N][DIM] bf16 unnormalized
    float* __restrict__ lpart)               // [2][H][N] fp32
{
    const int h  = blockIdx.y;
    const int ks = blockIdx.z;
    const int q0 = blockIdx.x * 256;
    const int kbase = ks * (NPTS / 2);
    const unsigned short* Q  = qg  + (size_t)h * NPTS * HDIM;
    const unsigned short* K  = kg  + (size_t)h * NPTS * HDIM;
    const unsigned short* Vt = vtg + (size_t)h * HDIM * NPTS;
    unsigned short* op = opart + (size_t)ks * NPTS * DIM;
    float* lp = lpart + (size_t)(ks * NHEAD + h) * NPTS;

    __shared__ __align__(16) unsigned short Klds[2][64 * 64];  // 16 KB
    __shared__ __align__(16) unsigned short Vlds[2][64 * 64];  // 16 KB

    const int t    = threadIdx.x;
    const int w    = t >> 6;
    const int lane = t & 63;
    const int l15  = lane & 15;
    const int quad = lane >> 4;

    const int koff0 = l15 * 64 + (quad ^ (l15 & 7)) * 8;
    const int koff1 = koff0 ^ 32;

    const int srow   = lane >> 3;
    const int schunk = (lane & 7) ^ srow;

    // Q B-frags: 4 m-tiles of 16 rows -> 64 q-rows per wave
    bf16x8 qf[4][2];
    #pragma unroll
    for (int m = 0; m < 4; ++m)
        #pragma unroll
        for (int kc = 0; kc < 2; ++kc)
            qf[m][kc] = *(const bf16x8*)
                &Q[(size_t)(q0 + 64 * w + 16 * m + l15) * HDIM + quad * 8 + 32 * kc];

    // all-ones bf16 A-frag for the row-sum MFMA (0x3F80 == bf16 1.0)
    const bf16x8 ones = {(short)0x3F80, (short)0x3F80, (short)0x3F80,
                         (short)0x3F80, (short)0x3F80, (short)0x3F80,
                         (short)0x3F80, (short)0x3F80};
    // persistent zero C-in: seeds each st accumulation without fresh movs
    const f32x4 Z0 = (f32x4){0.f, 0.f, 0.f, 0.f};

    // O^T accumulators [te][m]: row=quad*4+r -> e, col=l15 -> qrow
    f32x4 OT[4][4];
    f32x4 Lacc[4];
    #pragma unroll
    for (int te = 0; te < 4; ++te)
        #pragma unroll
        for (int m = 0; m < 4; ++m) OT[te][m] = (f32x4){0.f, 0.f, 0.f, 0.f};
    #pragma unroll
    for (int m = 0; m < 4; ++m) Lacc[m] = (f32x4){0.f, 0.f, 0.f, 0.f};

    // running staging pointers (advanced by constant strides inside STAGE_TILE)
    const unsigned short* Kp  = K  + (size_t)(kbase + 16 * w + srow) * HDIM
                                   + schunk * 8;
    const unsigned short* Vp0 = Vt + (size_t)(16 * w + srow) * NPTS
                                   + kbase + schunk * 8;
    const unsigned short* Vp1 = Vp0 + (size_t)8 * NPTS;

    STAGE_TILE(0);
    __syncthreads();
    int buf = 0;

    for (int kt = 0; kt < NPTS / 2; kt += 64) {
        // issue next stage first: a full body of latency cover before the
        // barrier's vmcnt(0) drain
        if (kt + 64 < NPTS / 2) {
            const int nxt = buf ^ 1;
            if (nxt) STAGE_TILE(1); else STAGE_TILE(0);
        }

        bf16x8 pt[2][4];

        // ---- subphase kb=0: keys 0..31 of the tile (kn slots 0,1) ----
        {
            bf16x8 kf[2][2];
            #pragma unroll
            for (int kn = 0; kn < 2; ++kn) {
                kf[kn][0] = *(const bf16x8*)&Klds[buf][1024 * kn + koff0];
                kf[kn][1] = *(const bf16x8*)&Klds[buf][1024 * kn + koff1];
            }
            f32x4 st[2][4];
            __builtin_amdgcn_s_setprio(1);
            #pragma unroll
            for (int kn = 0; kn < 2; ++kn)
                #pragma unroll
                for (int m = 0; m < 4; ++m) {
                    st[kn][m] = __builtin_amdgcn_mfma_f32_16x16x32_bf16(
                        kf[kn][0], qf[m][0], Z0, 0, 0, 0);
                    st[kn][m] = __builtin_amdgcn_mfma_f32_16x16x32_bf16(
                        kf[kn][1], qf[m][1], st[kn][m], 0, 0, 0);
                }
            __builtin_amdgcn_s_setprio(0);
            #pragma unroll
            for (int m = 0; m < 4; ++m) {
                float e0 = EXP2F(st[0][m][0]);
                float e1 = EXP2F(st[0][m][1]);
                float e2 = EXP2F(st[0][m][2]);
                float e3 = EXP2F(st[0][m][3]);
                float e4 = EXP2F(st[1][m][0]);
                float e5 = EXP2F(st[1][m][1]);
                float e6 = EXP2F(st[1][m][2]);
                float e7 = EXP2F(st[1][m][3]);
                union { uint4 u; bf16x8 v; } uu;
                uu.u.x = pk2bf(e0, e1);
                uu.u.y = pk2bf(e2, e3);
                uu.u.z = pk2bf(e4, e5);
                uu.u.w = pk2bf(e6, e7);
                pt[0][m] = uu.v;
            }
        }

        // V A-frags te=0,1 issued here: LDS reads drain under the kb=1 QK
        // MFMA burst (R13 overlap lesson)
        bf16x8 vf0[2][2];
        #pragma unroll
        for (int te = 0; te < 2; ++te) {
            vf0[te][0] = *(const bf16x8*)&Vlds[buf][1024 * te + koff0];
            vf0[te][1] = *(const bf16x8*)&Vlds[buf][1024 * te + koff1];
        }

        // ---- subphase kb=1: keys 32..63 of the tile (kn slots 2,3) ----
        {
            bf16x8 kf[2][2];
            #pragma unroll
            for (int kn = 0; kn < 2; ++kn) {
                kf[kn][0] = *(const bf16x8*)&Klds[buf][1024 * (kn + 2) + koff0];
                kf[kn][1] = *(const bf16x8*)&Klds[buf][1024 * (kn + 2) + koff1];
            }
            f32x4 st[2][4];
            __builtin_amdgcn_s_setprio(1);
            #pragma unroll
            for (int kn = 0; kn < 2; ++kn)
                #pragma unroll
                for (int m = 0; m < 4; ++m) {
                    st[kn][m] = __builtin_amdgcn_mfma_f32_16x16x32_bf16(
                        kf[kn][0], qf[m][0], Z0, 0, 0, 0);
                    st[kn][m] = __builtin_amdgcn_mfma_f32_16x16x32_bf16(
                        kf[kn][1], qf[m][1], st[kn][m], 0, 0, 0);
                }
            __builtin_amdgcn_s_setprio(0);
            #pragma unroll
            for (int m = 0; m < 4; ++m) {
                float e0 = EXP2F(st[0][m][0]);
                float e1 = EXP2F(st[0][m][1]);
                float e2 = EXP2F(st[0][m][2]);
                float e3 = EXP2F(st[0][m][3]);
                float e4 = EXP2F(st[1][m][0]);
                float e5 = EXP2F(st[1][m][1]);
                float e6 = EXP2F(st[1][m][2]);
                float e7 = EXP2F(st[1][m][3]);
                union { uint4 u; bf16x8 v; } uu;
                uu.u.x = pk2bf(e0, e1);
                uu.u.y = pk2bf(e2, e3);
                uu.u.z = pk2bf(e4, e5);
                uu.u.w = pk2bf(e6, e7);
                pt[1][m] = uu.v;
            }
        }

        // V A-frags te=2,3: drain under Lacc + PV-te01 MFMAs
        bf16x8 vf1[2][2];
        #pragma unroll
        for (int te = 0; te < 2; ++te) {
            vf1[te][0] = *(const bf16x8*)&Vlds[buf][1024 * (te + 2) + koff0];
            vf1[te][1] = *(const bf16x8*)&Vlds[buf][1024 * (te + 2) + koff1];
        }

        __builtin_amdgcn_s_setprio(1);
        // row-sum in the matrix pipe: Lacc[m] += ones x pt (all rows equal l)
        #pragma unroll
        for (int kb = 0; kb < 2; ++kb)
            #pragma unroll
            for (int m = 0; m < 4; ++m)
                Lacc[m] = __builtin_amdgcn_mfma_f32_16x16x32_bf16(
                    ones, pt[kb][m], Lacc[m], 0, 0, 0);

        // O^T += V^T P^T  (pure register path); te01 first (vf0 ready),
        // te23 last (vf1 reads covered by the MFMAs above)
        #pragma unroll
        for (int te = 0; te < 2; ++te)
            #pragma unroll
            for (int m = 0; m < 4; ++m) {
                OT[te][m] = __builtin_amdgcn_mfma_f32_16x16x32_bf16(
                    vf0[te][0], pt[0][m], OT[te][m], 0, 0, 0);
                OT[te][m] = __builtin_amdgcn_mfma_f32_16x16x32_bf16(
                    vf0[te][1], pt[1][m], OT[te][m], 0, 0, 0);
            }
        #pragma unroll
        for (int te = 0; te < 2; ++te)
            #pragma unroll
            for (int m = 0; m < 4; ++m) {
                OT[te + 2][m] = __builtin_amdgcn_mfma_f32_16x16x32_bf16(
                    vf1[te][0], pt[0][m], OT[te + 2][m], 0, 0, 0);
                OT[te + 2][m] = __builtin_amdgcn_mfma_f32_16x16x32_bf16(
                    vf1[te][1], pt[1][m], OT[te + 2][m], 0, 0, 0);
            }
        __builtin_amdgcn_s_setprio(0);

        __syncthreads();   // Klds/Vlds[buf] reads done; next stage visible
        buf ^= 1;
    }

    // epilogue: l comes straight out of Lacc (all components/quads equal);
    // write unnormalized O^T packed
    #pragma unroll
    for (int m = 0; m < 4; ++m) {
        int n = q0 + 64 * w + 16 * m + l15;
        if (quad == 0) lp[n] = Lacc[m][0];
        #pragma unroll
        for (int te = 0; te < 4; ++te) {
            uint2 pk;
            pk.x = pk2bf(OT[te][m][0], OT[te][m][1]);
            pk.y = pk2bf(OT[te][m][2], OT[te][m][3]);
            *(uint2*)&op[(size_t)n * DIM + h * HDIM + 16 * te + quad * 4] = pk;
        }
    }
}

// ---------------------------------------------------------------------------
// Output projection + k-split merge fused (R17), R18: full wot c0-tile
// (64 KB) staged in LDS once; barrier-free 8-step k-loop of {af loads ->
// LDS reads -> MFMA}; O += Os * inv with inv = 1/(l0+l1).
// ---------------------------------------------------------------------------
__global__ __launch_bounds__(256) void out_mfma_kernel(
    const unsigned short* __restrict__ op0,   // [N][512] bf16 unnormalized
    const unsigned short* __restrict__ op1,   // [N][512] bf16 unnormalized
    const float* __restrict__ l0,             // [H][N] fp32
    const float* __restrict__ l1,             // [H][N] fp32
    const unsigned short* __restrict__ wot,   // [512][512] bf16 [e_out][k]
    const float* __restrict__ bo, const float* __restrict__ x,
    float* __restrict__ outp)
{
    const int t = threadIdx.x, w = t >> 6, lane = t & 63;
    const int l15 = lane & 15, quad = lane >> 4;
    const int r0 = blockIdx.x * 128 + w * 32;
    const int c0 = blockIdx.y * 64;

    __shared__ __align__(16) unsigned short Wlds[8][64 * 64];  // 64 KB

    const int koff0 = l15 * 64 + (quad ^ (l15 & 7)) * 8;
    const int koff1 = koff0 ^ 32;
    const int srow   = lane >> 3;
    const int schunk = (lane & 7) ^ srow;

    const f32x4 Z0 = (f32x4){0.f, 0.f, 0.f, 0.f};

    // stage the whole [c0..c0+63] x [0..511] wot tile: 8 regions of 64x64
    {
        const unsigned short* Wb = wot + (size_t)(c0 + 16 * w + srow) * DIM
                                       + schunk * 8;
        #pragma unroll
        for (int kc = 0; kc < 8; ++kc) {
            __builtin_amdgcn_global_load_lds(
                (const GLOBAL_AS void*)(Wb + kc * 64),
                (LDS_AS void*)&Wlds[kc][(16 * w) * 64], 16, 0, 0);
            __builtin_amdgcn_global_load_lds(
                (const GLOBAL_AS void*)(Wb + (size_t)8 * DIM + kc * 64),
                (LDS_AS void*)&Wlds[kc][(16 * w + 8) * 64], 16, 0, 0);
        }
    }
    __syncthreads();

    f32x4 O[2][4];
    #pragma unroll
    for (int mt = 0; mt < 2; ++mt)
        #pragma unroll
        for (int tn = 0; tn < 4; ++tn) O[mt][tn] = (f32x4){0.f, 0.f, 0.f, 0.f};

    #pragma unroll
    for (int h = 0; h < 8; ++h) {
        const int k0 = h * 64;

        // unnormalized A-frags from both k-split halves (long latency first)
        bf16x8 af0[2][2], af1[2][2];
        #pragma unroll
        for (int mt = 0; mt < 2; ++mt)
            #pragma unroll
            for (int kc = 0; kc < 2; ++kc) {
                size_t idx = (size_t)(r0 + 16 * mt + l15) * DIM
                             + k0 + quad * 8 + 32 * kc;
                af0[mt][kc] = *(const bf16x8*)&op0[idx];
                af1[mt][kc] = *(const bf16x8*)&op1[idx];
            }

        // inv per (mt, r): rows n = r0+16mt+quad*4+r, head h (float4 loads)
        float inv0[4], inv1[4];
        {
            const float4 a0 = *(const float4*)&l0[(size_t)h * NPTS + r0 + quad * 4];
            const float4 b0 = *(const float4*)&l1[(size_t)h * NPTS + r0 + quad * 4];
            const float4 a1 = *(const float4*)&l0[(size_t)h * NPTS + r0 + 16 + quad * 4];
            const float4 b1 = *(const float4*)&l1[(size_t)h * NPTS + r0 + 16 + quad * 4];
            inv0[0] = 1.0f / (a0.x + b0.x); inv0[1] = 1.0f / (a0.y + b0.y);
            inv0[2] = 1.0f / (a0.z + b0.z); inv0[3] = 1.0f / (a0.w + b0.w);
            inv1[0] = 1.0f / (a1.x + b1.x); inv1[1] = 1.0f / (a1.y + b1.y);
            inv1[2] = 1.0f / (a1.z + b1.z); inv1[3] = 1.0f / (a1.w + b1.w);
        }

        // bf from LDS region h
        bf16x8 bf[4][2];
        #pragma unroll
        for (int tn = 0; tn < 4; ++tn) {
            bf[tn][0] = *(const bf16x8*)&Wlds[h][1024 * tn + koff0];
            bf[tn][1] = *(const bf16x8*)&Wlds[h][1024 * tn + koff1];
        }

        // per-k-step partial: Os = (af0 + af1) x bf  (4 chained MFMAs)
        #pragma unroll
        for (int mt = 0; mt < 2; ++mt) {
            const float* inv = (mt == 0) ? inv0 : inv1;
            #pragma unroll
            for (int tn = 0; tn < 4; ++tn) {
                f32x4 Os;
                Os = __builtin_amdgcn_mfma_f32_16x16x32_bf16(
                    af0[mt][0], bf[tn][0], Z0, 0, 0, 0);
                Os = __builtin_amdgcn_mfma_f32_16x16x32_bf16(
                    af0[mt][1], bf[tn][1], Os, 0, 0, 0);
                Os = __builtin_amdgcn_mfma_f32_16x16x32_bf16(
                    af1[mt][0], bf[tn][0], Os, 0, 0, 0);
                Os = __builtin_amdgcn_mfma_f32_16x16x32_bf16(
                    af1[mt][1], bf[tn][1], Os, 0, 0, 0);
                #pragma unroll
                for (int r = 0; r < 4; ++r)
                    O[mt][tn][r] += Os[r] * inv[r];
            }
        }
    }

    #pragma unroll
    for (int mt = 0; mt < 2; ++mt)
        #pragma unroll
        for (int tn = 0; tn < 4; ++tn) {
            int e = c0 + l15 + 16 * tn;
            float be = bo[e];
            #pragma unroll
            for (int r = 0; r < 4; ++r) {
                int n = r0 + 16 * mt + quad * 4 + r;
                outp[(size_t)n * DIM + e] = O[mt][tn][r] + be + x[(size_t)n * DIM + e];
            }
        }
}

extern "C" void kernel_launch(void* const* d_in, const int* in_sizes, int n_in,
                              void* d_out, int out_size, void* d_ws, size_t ws_size,
                              hipStream_t stream) {
    const float* x  = (const float*)d_in[0];
    const float* Wq = (const float*)d_in[1];
    const float* bq = (const float*)d_in[2];
    const float* Wk = (const float*)d_in[3];
    const float* bk = (const float*)d_in[4];
    const float* Wv = (const float*)d_in[5];
    const float* bv = (const float*)d_in[6];
    const float* Wo = (const float*)d_in[7];
    const float* bo = (const float*)d_in[8];
    float* out = (float*)d_out;

    const size_t per = (size_t)NHEAD * NPTS * HDIM;            // 4M elems
    unsigned short* xbf   = (unsigned short*)d_ws;             //  8 MB
    unsigned short* wtq   = xbf + (size_t)NPTS * DIM;          //  1.5 MB
    unsigned short* wot   = wtq + (size_t)24 * HDIM * DIM;     //  0.5 MB
    unsigned short* q_bf  = wot + (size_t)DIM * DIM;           //  8 MB
    unsigned short* k_bf  = q_bf + per;                        //  8 MB
    unsigned short* vt_bf = k_bf + per;                        //  8 MB
    unsigned short* op0   = vt_bf + per;                       //  8 MB
    unsigned short* op1   = op0 + (size_t)NPTS * DIM;          //  8 MB
    float*          lpart = (float*)(op1 + (size_t)NPTS * DIM); // 512 KB
    // total ws: ~50.5 MB

    prep_kernel<<<dim3(2304), 256, 0, stream>>>(
        x, xbf, Wq, Wk, Wv, wtq, Wo, wot);
    qkv_mfma_kernel<<<dim3(NPTS / 128, 24), 256, 0, stream>>>(
        xbf, wtq, bq, bk, bv, q_bf, k_bf, vt_bf);
    attn_kernel<<<dim3(NPTS / 256, NHEAD, 2), 256, 0, stream>>>(
        q_bf, k_bf, vt_bf, op0, lpart);
    out_mfma_kernel<<<dim3(NPTS / 128, DIM / 64), 256, 0, stream>>>(
        op0, op1, lpart, lpart + (size_t)NHEAD * NPTS, wot, bo, x, out);
}

// Round 17
// 274.737 us; speedup vs baseline: 1.0948x; 1.0174x over previous
//
#include <hip/hip_runtime.h>
#include <hip/hip_bf16.h>

#define NPTS 8192
#define DIM  512
#define NHEAD 8
#define HDIM 64

typedef short bf16x8 __attribute__((ext_vector_type(8)));   // 8 bf16 = 4 VGPRs
typedef float f32x4  __attribute__((ext_vector_type(4)));   // MFMA C/D

#define GLOBAL_AS __attribute__((address_space(1)))
#define LDS_AS    __attribute__((address_space(3)))

#if __has_builtin(__builtin_amdgcn_exp2f)
#define EXP2F(x) __builtin_amdgcn_exp2f(x)
#else
#define EXP2F(x) __expf((x) * 0.6931471805599453f)
#endif

// fp32 -> bf16 round-nearest-even (scalar)
__device__ __forceinline__ unsigned short f2bf(float f) {
    union { float f; unsigned int u; } v; v.f = f;
    unsigned int r = v.u + 0x7FFFu + ((v.u >> 16) & 1u);
    return (unsigned short)(r >> 16);
}
__device__ __forceinline__ float bf2f(unsigned short u) {
    union { unsigned int i; float f; } v; v.i = ((unsigned int)u) << 16;
    return v.f;
}
// packed 2x f32 -> bf16 pair (v_cvt_pk_bf16_f32 on gfx950)
__device__ __forceinline__ unsigned int pk2bf(float a, float b) {
    __hip_bfloat162 h = __float22bfloat162_rn(float2{a, b});
    union { __hip_bfloat162 h; unsigned int u; } v; v.h = h;
    return v.u;
}

// ---------------------------------------------------------------------------
// Merged prep kernel (R18): cvt_x (blocks 0..2047), tr_w (2048..2239),
// tr_wo (2240..2303). Branches are block-uniform; saves 2 kernel launches.
// ---------------------------------------------------------------------------
__global__ __launch_bounds__(256) void prep_kernel(
    const float* __restrict__ xin, unsigned short* __restrict__ xbf,
    const float* __restrict__ Wq, const float* __restrict__ Wk,
    const float* __restrict__ Wv, unsigned short* __restrict__ wtq,
    const float* __restrict__ Wo, unsigned short* __restrict__ wot)
{
    const int bid = blockIdx.x;
    const int t = threadIdx.x;

    if (bid < 2048) {
        // ---- cvt_x: x fp32 -> bf16, 8 elems/thread ----
        int gid = bid * 256 + t;
        float4 a = ((const float4*)xin)[gid * 2];
        float4 b = ((const float4*)xin)[gid * 2 + 1];
        uint4 u;
        u.x = pk2bf(a.x, a.y); u.y = pk2bf(a.z, a.w);
        u.z = pk2bf(b.x, b.y); u.w = pk2bf(b.z, b.w);
        ((uint4*)xbf)[gid] = u;
        return;
    }

    __shared__ float tile[64][65];
    int c = t & 63, r = t >> 6;

    if (bid < 2240) {
        // ---- tr_w: Wq/Wk/Wv [h][512][64] -> wtq [zh][64][512] bf16 ----
        int idx = bid - 2048;
        int k0 = (idx & 7) * 64;
        int zh = idx >> 3, z = zh >> 3, h = zh & 7;
        const float* src = (z == 0 ? Wq : z == 1 ? Wk : Wv)
                           + (size_t)h * DIM * HDIM;
        unsigned short* dst = wtq + (size_t)zh * HDIM * DIM;
        #pragma unroll
        for (int i = 0; i < 16; ++i)
            tile[r + 4 * i][c] = src[(size_t)(k0 + r + 4 * i) * HDIM + c];
        __syncthreads();
        #pragma unroll
        for (int i = 0; i < 16; ++i)
            dst[(size_t)(r + 4 * i) * DIM + k0 + c] = f2bf(tile[c][r + 4 * i]);
    } else {
        // ---- tr_wo: Wo [512][512] -> wot [512][512] bf16 transposed ----
        int idx = bid - 2240;
        int k0 = (idx & 7) * 64, e0 = (idx >> 3) * 64;
        #pragma unroll
        for (int i = 0; i < 16; ++i)
            tile[r + 4 * i][c] = Wo[(size_t)(k0 + r + 4 * i) * DIM + e0 + c];
        __syncthreads();
        #pragma unroll
        for (int i = 0; i < 16; ++i)
            wot[(size_t)(e0 + r + 4 * i) * DIM + k0 + c] = f2bf(tile[c][r + 4 * i]);
    }
}

// ---------------------------------------------------------------------------
// QKV projection, bf16 MFMA. R16 structure + R21: T5 s_setprio around the
// MFMA cluster (same mechanism as attn's R20 win: 3-4 barrier-independent
// blocks/CU alternate MFMA and staging phases; priority lets MFMA-phase
// waves preempt issue slots).
//   z=0: q_bf[h][n][e]  (scale*log2e folded)   z=1: k_bf[h][n][e]
//   z=2: vtp[h][e][pi(n)] = V^T with the PV sigma-permutation pre-applied.
// ---------------------------------------------------------------------------
__global__ __launch_bounds__(256) void qkv_mfma_kernel(
    const unsigned short* __restrict__ xbf,   // [N][512] bf16
    const unsigned short* __restrict__ wtq,   // [24][64][512] bf16
    const float* __restrict__ bq, const float* __restrict__ bk,
    const float* __restrict__ bv,
    unsigned short* __restrict__ q_bf, unsigned short* __restrict__ k_bf,
    unsigned short* __restrict__ vt_bf)
{
    const int zh = blockIdx.y, z = zh >> 3, h = zh & 7;
    const unsigned short* W = wtq + (size_t)zh * HDIM * DIM;
    const float* b = (z == 0 ? bq : z == 1 ? bk : bv) + h * HDIM;
    const int t = threadIdx.x, w = t >> 6, lane = t & 63;
    const int l15 = lane & 15, quad = lane >> 4;
    const int r0 = blockIdx.x * 128 + w * 32;

    __shared__ __align__(16) unsigned short Wlds[2][64 * 64];  // 2 x 8 KB

    const int koff0 = l15 * 64 + (quad ^ (l15 & 7)) * 8;
    const int koff1 = koff0 ^ 32;
    const int srow   = lane >> 3;
    const int schunk = (lane & 7) ^ srow;

    const unsigned short* Wp = W + (size_t)(16 * w + srow) * DIM + schunk * 8;

    __builtin_amdgcn_global_load_lds((const GLOBAL_AS void*)Wp,
        (LDS_AS void*)&Wlds[0][(16 * w) * 64], 16, 0, 0);
    __builtin_amdgcn_global_load_lds((const GLOBAL_AS void*)(Wp + (size_t)8 * DIM),
        (LDS_AS void*)&Wlds[0][(16 * w + 8) * 64], 16, 0, 0);
    Wp += 64;
    __syncthreads();
    int buf = 0;

    f32x4 O[2][4];
    #pragma unroll
    for (int mt = 0; mt < 2; ++mt)
        #pragma unroll
        for (int tn = 0; tn < 4; ++tn) O[mt][tn] = (f32x4){0.f, 0.f, 0.f, 0.f};

    for (int k0 = 0; k0 < DIM; k0 += 64) {
        if (k0 + 64 < DIM) {
            int nb = buf ^ 1;
            __builtin_amdgcn_global_load_lds((const GLOBAL_AS void*)Wp,
                (LDS_AS void*)&Wlds[nb][(16 * w) * 64], 16, 0, 0);
            __builtin_amdgcn_global_load_lds(
                (const GLOBAL_AS void*)(Wp + (size_t)8 * DIM),
                (LDS_AS void*)&Wlds[nb][(16 * w + 8) * 64], 16, 0, 0);
            Wp += 64;
        }

        bf16x8 af[2][2];
        #pragma unroll
        for (int mt = 0; mt < 2; ++mt)
            #pragma unroll
            for (int kc = 0; kc < 2; ++kc)
                af[mt][kc] = *(const bf16x8*)
                    &xbf[(size_t)(r0 + 16 * mt + l15) * DIM + k0 + quad * 8 + 32 * kc];

        bf16x8 bf[4][2];
        #pragma unroll
        for (int tn = 0; tn < 4; ++tn) {
            bf[tn][0] = *(const bf16x8*)&Wlds[buf][1024 * tn + koff0];
            bf[tn][1] = *(const bf16x8*)&Wlds[buf][1024 * tn + koff1];
        }

        __builtin_amdgcn_s_setprio(1);
        #pragma unroll
        for (int mt = 0; mt < 2; ++mt)
            #pragma unroll
            for (int tn = 0; tn < 4; ++tn) {
                O[mt][tn] = __builtin_amdgcn_mfma_f32_16x16x32_bf16(
                    af[mt][0], bf[tn][0], O[mt][tn], 0, 0, 0);
                O[mt][tn] = __builtin_amdgcn_mfma_f32_16x16x32_bf16(
                    af[mt][1], bf[tn][1], O[mt][tn], 0, 0, 0);
            }
        __builtin_amdgcn_s_setprio(0);

        __syncthreads();
        buf ^= 1;
    }

    if (z < 2) {
        unsigned short* outp = (z == 0 ? q_bf : k_bf) + (size_t)h * NPTS * HDIM;
        const float sc = (z == 0) ? 0.18033688011112042f : 1.0f;  // 0.125*log2e | 1
        #pragma unroll
        for (int mt = 0; mt < 2; ++mt)
            #pragma unroll
            for (int tn = 0; tn < 4; ++tn) {
                int e = l15 + 16 * tn;
                float be = b[e];
                #pragma unroll
                for (int r = 0; r < 4; ++r) {
                    int n = r0 + 16 * mt + quad * 4 + r;
                    outp[(size_t)n * HDIM + e] = f2bf((O[mt][tn][r] + be) * sc);
                }
            }
    } else {
        unsigned short* vt = vt_bf + (size_t)h * HDIM * NPTS;
        #pragma unroll
        for (int mt = 0; mt < 2; ++mt)
            #pragma unroll
            for (int tn = 0; tn < 4; ++tn) {
                int e = l15 + 16 * tn;
                float be = b[e];
                uint2 pk;
                pk.x = pk2bf(O[mt][tn][0] + be, O[mt][tn][1] + be);
                pk.y = pk2bf(O[mt][tn][2] + be, O[mt][tn][3] + be);
                // sigma-permuted position within this 32-row block
                *(uint2*)&vt[(size_t)e * NPTS + r0 + quad * 8 + mt * 4] = pk;
            }
    }
}

// ---------------------------------------------------------------------------
// MFMA flash attention, R20 (kept verbatim, 165.8us): R14b structure + T5
// s_setprio around the three MFMA clusters (+4.3% measured). k-split 2.
// Sentinels: VGPR 120, WRITE 16.9 MB. ~99% issue saturation.
// ---------------------------------------------------------------------------
#define STAGE_TILE(B)                                                         \
    do {                                                                      \
        __builtin_amdgcn_global_load_lds((const GLOBAL_AS void*)Kp,           \
            (LDS_AS void*)&Klds[B][(16 * w) * 64], 16, 0, 0);                 \
        __builtin_amdgcn_global_load_lds((const GLOBAL_AS void*)(Kp + 8 * HDIM), \
            (LDS_AS void*)&Klds[B][(16 * w + 8) * 64], 16, 0, 0);             \
        __builtin_amdgcn_global_load_lds((const GLOBAL_AS void*)Vp0,          \
            (LDS_AS void*)&Vlds[B][(16 * w) * 64], 16, 0, 0);                 \
        __builtin_amdgcn_global_load_lds((const GLOBAL_AS void*)Vp1,          \
            (LDS_AS void*)&Vlds[B][(16 * w + 8) * 64], 16, 0, 0);             \
        Kp += 64 * HDIM; Vp0 += 64; Vp1 += 64;                                \
    } while (0)

__global__ __launch_bounds__(256) void attn_kernel(
    const unsigned short* __restrict__ qg,   // [H][N][64] bf16, pre-scaled
    const unsigned short* __restrict__ kg,   // [H][N][64] bf16
    const unsigned short* __restrict__ vtg,  // [H][64][N] bf16, sigma-permuted
    unsigned short* __restrict__ opart,      // [2][N][DIM] bf16 unnormalized
    float* __restrict__ lpart)               // [2][H][N] fp32
{
    const int h  = blockIdx.y;
    const int ks = blockIdx.z;
    const int q0 = blockIdx.x * 256;
    const int kbase = ks * (NPTS / 2);
    const unsigned short* Q  = qg  + (size_t)h * NPTS * HDIM;
    const unsigned short* K  = kg  + (size_t)h * NPTS * HDIM;
    const unsigned short* Vt = vtg + (size_t)h * HDIM * NPTS;
    unsigned short* op = opart + (size_t)ks * NPTS * DIM;
    float* lp = lpart + (size_t)(ks * NHEAD + h) * NPTS;

    __shared__ __align__(16) unsigned short Klds[2][64 * 64];  // 16 KB
    __shared__ __align__(16) unsigned short Vlds[2][64 * 64];  // 16 KB

    const int t    = threadIdx.x;
    const int w    = t >> 6;
    const int lane = t & 63;
    const int l15  = lane & 15;
    const int quad = lane >> 4;

    const int koff0 = l15 * 64 + (quad ^ (l15 & 7)) * 8;
    const int koff1 = koff0 ^ 32;

    const int srow   = lane >> 3;
    const int schunk = (lane & 7) ^ srow;

    // Q B-frags: 4 m-tiles of 16 rows -> 64 q-rows per wave
    bf16x8 qf[4][2];
    #pragma unroll
    for (int m = 0; m < 4; ++m)
        #pragma unroll
        for (int kc = 0; kc < 2; ++kc)
            qf[m][kc] = *(const bf16x8*)
                &Q[(size_t)(q0 + 64 * w + 16 * m + l15) * HDIM + quad * 8 + 32 * kc];

    // all-ones bf16 A-frag for the row-sum MFMA (0x3F80 == bf16 1.0)
    const bf16x8 ones = {(short)0x3F80, (short)0x3F80, (short)0x3F80,
                         (short)0x3F80, (short)0x3F80, (short)0x3F80,
                         (short)0x3F80, (short)0x3F80};
    // persistent zero C-in: seeds each st accumulation without fresh movs
    const f32x4 Z0 = (f32x4){0.f, 0.f, 0.f, 0.f};

    // O^T accumulators [te][m]: row=quad*4+r -> e, col=l15 -> qrow
    f32x4 OT[4][4];
    f32x4 Lacc[4];
    #pragma unroll
    for (int te = 0; te < 4; ++te)
        #pragma unroll
        for (int m = 0; m < 4; ++m) OT[te][m] = (f32x4){0.f, 0.f, 0.f, 0.f};
    #pragma unroll
    for (int m = 0; m < 4; ++m) Lacc[m] = (f32x4){0.f, 0.f, 0.f, 0.f};

    // running staging pointers (advanced by constant strides inside STAGE_TILE)
    const unsigned short* Kp  = K  + (size_t)(kbase + 16 * w + srow) * HDIM
                                   + schunk * 8;
    const unsigned short* Vp0 = Vt + (size_t)(16 * w + srow) * NPTS
                                   + kbase + schunk * 8;
    const unsigned short* Vp1 = Vp0 + (size_t)8 * NPTS;

    STAGE_TILE(0);
    __syncthreads();
    int buf = 0;

    for (int kt = 0; kt < NPTS / 2; kt += 64) {
        // issue next stage first: a full body of latency cover before the
        // barrier's vmcnt(0) drain
        if (kt + 64 < NPTS / 2) {
            const int nxt = buf ^ 1;
            if (nxt) STAGE_TILE(1); else STAGE_TILE(0);
        }

        bf16x8 pt[2][4];

        // ---- subphase kb=0: keys 0..31 of the tile (kn slots 0,1) ----
        {
            bf16x8 kf[2][2];
            #pragma unroll
            for (int kn = 0; kn < 2; ++kn) {
                kf[kn][0] = *(const bf16x8*)&Klds[buf][1024 * kn + koff0];
                kf[kn][1] = *(const bf16x8*)&Klds[buf][1024 * kn + koff1];
            }
            f32x4 st[2][4];
            __builtin_amdgcn_s_setprio(1);
            #pragma unroll
            for (int kn = 0; kn < 2; ++kn)
                #pragma unroll
                for (int m = 0; m < 4; ++m) {
                    st[kn][m] = __builtin_amdgcn_mfma_f32_16x16x32_bf16(
                        kf[kn][0], qf[m][0], Z0, 0, 0, 0);
                    st[kn][m] = __builtin_amdgcn_mfma_f32_16x16x32_bf16(
                        kf[kn][1], qf[m][1], st[kn][m], 0, 0, 0);
                }
            __builtin_amdgcn_s_setprio(0);
            #pragma unroll
            for (int m = 0; m < 4; ++m) {
                float e0 = EXP2F(st[0][m][0]);
                float e1 = EXP2F(st[0][m][1]);
                float e2 = EXP2F(st[0][m][2]);
                float e3 = EXP2F(st[0][m][3]);
                float e4 = EXP2F(st[1][m][0]);
                float e5 = EXP2F(st[1][m][1]);
                float e6 = EXP2F(st[1][m][2]);
                float e7 = EXP2F(st[1][m][3]);
                union { uint4 u; bf16x8 v; } uu;
                uu.u.x = pk2bf(e0, e1);
                uu.u.y = pk2bf(e2, e3);
                uu.u.z = pk2bf(e4, e5);
                uu.u.w = pk2bf(e6, e7);
                pt[0][m] = uu.v;
            }
        }

        // V A-frags te=0,1 issued here: LDS reads drain under the kb=1 QK
        // MFMA burst (R13 overlap lesson)
        bf16x8 vf0[2][2];
        #pragma unroll
        for (int te = 0; te < 2; ++te) {
            vf0[te][0] = *(const bf16x8*)&Vlds[buf][1024 * te + koff0];
            vf0[te][1] = *(const bf16x8*)&Vlds[buf][1024 * te + koff1];
        }

        // ---- subphase kb=1: keys 32..63 of the tile (kn slots 2,3) ----
        {
            bf16x8 kf[2][2];
            #pragma unroll
            for (int kn = 0; kn < 2; ++kn) {
                kf[kn][0] = *(const bf16x8*)&Klds[buf][1024 * (kn + 2) + koff0];
                kf[kn][1] = *(const bf16x8*)&Klds[buf][1024 * (kn + 2) + koff1];
            }
            f32x4 st[2][4];
            __builtin_amdgcn_s_setprio(1);
            #pragma unroll
            for (int kn = 0; kn < 2; ++kn)
                #pragma unroll
                for (int m = 0; m < 4; ++m) {
                    st[kn][m] = __builtin_amdgcn_mfma_f32_16x16x32_bf16(
                        kf[kn][0], qf[m][0], Z0, 0, 0, 0);
                    st[kn][m] = __builtin_amdgcn_mfma_f32_16x16x32_bf16(
                        kf[kn][1], qf[m][1], st[kn][m], 0, 0, 0);
                }
            __builtin_amdgcn_s_setprio(0);
            #pragma unroll
            for (int m = 0; m < 4; ++m) {
                float e0 = EXP2F(st[0][m][0]);
                float e1 = EXP2F(st[0][m][1]);
                float e2 = EXP2F(st[0][m][2]);
                float e3 = EXP2F(st[0][m][3]);
                float e4 = EXP2F(st[1][m][0]);
                float e5 = EXP2F(st[1][m][1]);
                float e6 = EXP2F(st[1][m][2]);
                float e7 = EXP2F(st[1][m][3]);
                union { uint4 u; bf16x8 v; } uu;
                uu.u.x = pk2bf(e0, e1);
                uu.u.y = pk2bf(e2, e3);
                uu.u.z = pk2bf(e4, e5);
                uu.u.w = pk2bf(e6, e7);
                pt[1][m] = uu.v;
            }
        }

        // V A-frags te=2,3: drain under Lacc + PV-te01 MFMAs
        bf16x8 vf1[2][2];
        #pragma unroll
        for (int te = 0; te < 2; ++te) {
            vf1[te][0] = *(const bf16x8*)&Vlds[buf][1024 * (te + 2) + koff0];
            vf1[te][1] = *(const bf16x8*)&Vlds[buf][1024 * (te + 2) + koff1];
        }

        __builtin_amdgcn_s_setprio(1);
        // row-sum in the matrix pipe: Lacc[m] += ones x pt (all rows equal l)
        #pragma unroll
        for (int kb = 0; kb < 2; ++kb)
            #pragma unroll
            for (int m = 0; m < 4; ++m)
                Lacc[m] = __builtin_amdgcn_mfma_f32_16x16x32_bf16(
                    ones, pt[kb][m], Lacc[m], 0, 0, 0);

        // O^T += V^T P^T  (pure register path); te01 first (vf0 ready),
        // te23 last (vf1 reads covered by the MFMAs above)
        #pragma unroll
        for (int te = 0; te < 2; ++te)
            #pragma unroll
            for (int m = 0; m < 4; ++m) {
                OT[te][m] = __builtin_amdgcn_mfma_f32_16x16x32_bf16(
                    vf0[te][0], pt[0][m], OT[te][m], 0, 0, 0);
                OT[te][m] = __builtin_amdgcn_mfma_f32_16x16x32_bf16(
                    vf0[te][1], pt[1][m], OT[te][m], 0, 0, 0);
            }
        #pragma unroll
        for (int te = 0; te < 2; ++te)
            #pragma unroll
            for (int m = 0; m < 4; ++m) {
                OT[te + 2][m] = __builtin_amdgcn_mfma_f32_16x16x32_bf16(
                    vf1[te][0], pt[0][m], OT[te + 2][m], 0, 0, 0);
                OT[te + 2][m] = __builtin_amdgcn_mfma_f32_16x16x32_bf16(
                    vf1[te][1], pt[1][m], OT[te + 2][m], 0, 0, 0);
            }
        __builtin_amdgcn_s_setprio(0);

        __syncthreads();   // Klds/Vlds[buf] reads done; next stage visible
        buf ^= 1;
    }

    // epilogue: l comes straight out of Lacc (all components/quads equal);
    // write unnormalized O^T packed
    #pragma unroll
    for (int m = 0; m < 4; ++m) {
        int n = q0 + 64 * w + 16 * m + l15;
        if (quad == 0) lp[n] = Lacc[m][0];
        #pragma unroll
        for (int te = 0; te < 4; ++te) {
            uint2 pk;
            pk.x = pk2bf(OT[te][m][0], OT[te][m][1]);
            pk.y = pk2bf(OT[te][m][2], OT[te][m][3]);
            *(uint2*)&op[(size_t)n * DIM + h * HDIM + 16 * te + quad * 4] = pk;
        }
    }
}

// ---------------------------------------------------------------------------
// Output projection + k-split merge fused (R17/R18) + R21 T5 setprio around
// the MFMA chain (2 blocks/CU alternate af-load and MFMA phases).
// ---------------------------------------------------------------------------
__global__ __launch_bounds__(256) void out_mfma_kernel(
    const unsigned short* __restrict__ op0,   // [N][512] bf16 unnormalized
    const unsigned short* __restrict__ op1,   // [N][512] bf16 unnormalized
    const float* __restrict__ l0,             // [H][N] fp32
    const float* __restrict__ l1,             // [H][N] fp32
    const unsigned short* __restrict__ wot,   // [512][512] bf16 [e_out][k]
    const float* __restrict__ bo, const float* __restrict__ x,
    float* __restrict__ outp)
{
    const int t = threadIdx.x, w = t >> 6, lane = t & 63;
    const int l15 = lane & 15, quad = lane >> 4;
    const int r0 = blockIdx.x * 128 + w * 32;
    const int c0 = blockIdx.y * 64;

    __shared__ __align__(16) unsigned short Wlds[8][64 * 64];  // 64 KB

    const int koff0 = l15 * 64 + (quad ^ (l15 & 7)) * 8;
    const int koff1 = koff0 ^ 32;
    const int srow   = lane >> 3;
    const int schunk = (lane & 7) ^ srow;

    const f32x4 Z0 = (f32x4){0.f, 0.f, 0.f, 0.f};

    // stage the whole [c0..c0+63] x [0..511] wot tile: 8 regions of 64x64
    {
        const unsigned short* Wb = wot + (size_t)(c0 + 16 * w + srow) * DIM
                                       + schunk * 8;
        #pragma unroll
        for (int kc = 0; kc < 8; ++kc) {
            __builtin_amdgcn_global_load_lds(
                (const GLOBAL_AS void*)(Wb + kc * 64),
                (LDS_AS void*)&Wlds[kc][(16 * w) * 64], 16, 0, 0);
            __builtin_amdgcn_global_load_lds(
                (const GLOBAL_AS void*)(Wb + (size_t)8 * DIM + kc * 64),
                (LDS_AS void*)&Wlds[kc][(16 * w + 8) * 64], 16, 0, 0);
        }
    }
    __syncthreads();

    f32x4 O[2][4];
    #pragma unroll
    for (int mt = 0; mt < 2; ++mt)
        #pragma unroll
        for (int tn = 0; tn < 4; ++tn) O[mt][tn] = (f32x4){0.f, 0.f, 0.f, 0.f};

    #pragma unroll
    for (int h = 0; h < 8; ++h) {
        const int k0 = h * 64;

        // unnormalized A-frags from both k-split halves (long latency first)
        bf16x8 af0[2][2], af1[2][2];
        #pragma unroll
        for (int mt = 0; mt < 2; ++mt)
            #pragma unroll
            for (int kc = 0; kc < 2; ++kc) {
                size_t idx = (size_t)(r0 + 16 * mt + l15) * DIM
                             + k0 + quad * 8 + 32 * kc;
                af0[mt][kc] = *(const bf16x8*)&op0[idx];
                af1[mt][kc] = *(const bf16x8*)&op1[idx];
            }

        // inv per (mt, r): rows n = r0+16mt+quad*4+r, head h (float4 loads)
        float inv0[4], inv1[4];
        {
            const float4 a0 = *(const float4*)&l0[(size_t)h * NPTS + r0 + quad * 4];
            const float4 b0 = *(const float4*)&l1[(size_t)h * NPTS + r0 + quad * 4];
            const float4 a1 = *(const float4*)&l0[(size_t)h * NPTS + r0 + 16 + quad * 4];
            const float4 b1 = *(const float4*)&l1[(size_t)h * NPTS + r0 + 16 + quad * 4];
            inv0[0] = 1.0f / (a0.x + b0.x); inv0[1] = 1.0f / (a0.y + b0.y);
            inv0[2] = 1.0f / (a0.z + b0.z); inv0[3] = 1.0f / (a0.w + b0.w);
            inv1[0] = 1.0f / (a1.x + b1.x); inv1[1] = 1.0f / (a1.y + b1.y);
            inv1[2] = 1.0f / (a1.z + b1.z); inv1[3] = 1.0f / (a1.w + b1.w);
        }

        // bf from LDS region h
        bf16x8 bf[4][2];
        #pragma unroll
        for (int tn = 0; tn < 4; ++tn) {
            bf[tn][0] = *(const bf16x8*)&Wlds[h][1024 * tn + koff0];
            bf[tn][1] = *(const bf16x8*)&Wlds[h][1024 * tn + koff1];
        }

        // per-k-step partial: Os = (af0 + af1) x bf  (4 chained MFMAs)
        __builtin_amdgcn_s_setprio(1);
        #pragma unroll
        for (int mt = 0; mt < 2; ++mt) {
            const float* inv = (mt == 0) ? inv0 : inv1;
            #pragma unroll
            for (int tn = 0; tn < 4; ++tn) {
                f32x4 Os;
                Os = __builtin_amdgcn_mfma_f32_16x16x32_bf16(
                    af0[mt][0], bf[tn][0], Z0, 0, 0, 0);
                Os = __builtin_amdgcn_mfma_f32_16x16x32_bf16(
                    af0[mt][1], bf[tn][1], Os, 0, 0, 0);
                Os = __builtin_amdgcn_mfma_f32_16x16x32_bf16(
                    af1[mt][0], bf[tn][0], Os, 0, 0, 0);
                Os = __builtin_amdgcn_mfma_f32_16x16x32_bf16(
                    af1[mt][1], bf[tn][1], Os, 0, 0, 0);
                #pragma unroll
                for (int r = 0; r < 4; ++r)
                    O[mt][tn][r] += Os[r] * inv[r];
            }
        }
        __builtin_amdgcn_s_setprio(0);
    }

    #pragma unroll
    for (int mt = 0; mt < 2; ++mt)
        #pragma unroll
        for (int tn = 0; tn < 4; ++tn) {
            int e = c0 + l15 + 16 * tn;
            float be = bo[e];
            #pragma unroll
            for (int r = 0; r < 4; ++r) {
                int n = r0 + 16 * mt + quad * 4 + r;
                outp[(size_t)n * DIM + e] = O[mt][tn][r] + be + x[(size_t)n * DIM + e];
            }
        }
}

extern "C" void kernel_launch(void* const* d_in, const int* in_sizes, int n_in,
                              void* d_out, int out_size, void* d_ws, size_t ws_size,
                              hipStream_t stream) {
    const float* x  = (const float*)d_in[0];
    const float* Wq = (const float*)d_in[1];
    const float* bq = (const float*)d_in[2];
    const float* Wk = (const float*)d_in[3];
    const float* bk = (const float*)d_in[4];
    const float* Wv = (const float*)d_in[5];
    const float* bv = (const float*)d_in[6];
    const float* Wo = (const float*)d_in[7];
    const float* bo = (const float*)d_in[8];
    float* out = (float*)d_out;

    const size_t per = (size_t)NHEAD * NPTS * HDIM;            // 4M elems
    unsigned short* xbf   = (unsigned short*)d_ws;             //  8 MB
    unsigned short* wtq   = xbf + (size_t)NPTS * DIM;          //  1.5 MB
    unsigned short* wot   = wtq + (size_t)24 * HDIM * DIM;     //  0.5 MB
    unsigned short* q_bf  = wot + (size_t)DIM * DIM;           //  8 MB
    unsigned short* k_bf  = q_bf + per;                        //  8 MB
    unsigned short* vt_bf = k_bf + per;                        //  8 MB
    unsigned short* op0   = vt_bf + per;                       //  8 MB
    unsigned short* op1   = op0 + (size_t)NPTS * DIM;          //  8 MB
    float*          lpart = (float*)(op1 + (size_t)NPTS * DIM); // 512 KB
    // total ws: ~50.5 MB

    prep_kernel<<<dim3(2304), 256, 0, stream>>>(
        x, xbf, Wq, Wk, Wv, wtq, Wo, wot);
    qkv_mfma_kernel<<<dim3(NPTS / 128, 24), 256, 0, stream>>>(
        xbf, wtq, bq, bk, bv, q_bf, k_bf, vt_bf);
    attn_kernel<<<dim3(NPTS / 256, NHEAD, 2), 256, 0, stream>>>(
        q_bf, k_bf, vt_bf, op0, lpart);
    out_mfma_kernel<<<dim3(NPTS / 128, DIM / 64), 256, 0, stream>>>(
        op0, op1, lpart, lpart + (size_t)NHEAD * NPTS, wot, bo, x, out);
}